// Round 3
// baseline (565.535 us; speedup 1.0000x reference)
//
#include <hip/hip_runtime.h>
#include <hip/hip_bf16.h>

typedef unsigned short ushort_t;
typedef __bf16 bf16_t;
typedef bf16_t bf16x8 __attribute__((ext_vector_type(8)));
typedef float floatx4 __attribute__((ext_vector_type(4)));
typedef ushort_t ushortx8 __attribute__((ext_vector_type(8)));

struct alignas(8) us4 { ushort_t x, y, z, w; };

__device__ __forceinline__ ushort_t f2bf(float f) {
  union { float f; unsigned int u; } v; v.f = f;
  unsigned int u = v.u;
  return (ushort_t)((u + 0x7fffu + ((u >> 16) & 1u)) >> 16);
}

__device__ __forceinline__ unsigned int pk_bf16(float a, float b) {
  __hip_bfloat162 h = __float22bfloat162_rn(float2{a, b});  // .x in low half
  union { __hip_bfloat162 h; unsigned int u; } v; v.h = h;
  return v.u;
}

__device__ __forceinline__ void async16(const void* g, void* l) {
  __builtin_amdgcn_global_load_lds(
      (const __attribute__((address_space(1))) unsigned int*)g,
      (__attribute__((address_space(3))) unsigned int*)l, 16, 0, 0);
}

#define LOG2E 1.44269504088896340736f

// ---------------- convert / transpose ----------------

__global__ __launch_bounds__(256) void k_cvt_x(const float* __restrict__ in,
                                               ushort_t* __restrict__ out) {
  size_t i = ((size_t)blockIdx.x * 256 + threadIdx.x) * 8;
  float4 a = *(const float4*)(in + i);
  float4 b = *(const float4*)(in + i + 4);
  ushortx8 o;
  o[0] = f2bf(a.x); o[1] = f2bf(a.y); o[2] = f2bf(a.z); o[3] = f2bf(a.w);
  o[4] = f2bf(b.x); o[5] = f2bf(b.y); o[6] = f2bf(b.z); o[7] = f2bf(b.w);
  *(ushortx8*)(out + i) = o;
}

__global__ __launch_bounds__(256) void k_transpose_bf16(const float* __restrict__ in,
                                                        ushort_t* __restrict__ out,
                                                        int R, int C) {
  __shared__ float tile[32][33];
  int c0 = blockIdx.x * 32, r0 = blockIdx.y * 32;
  int tx = threadIdx.x, ty = threadIdx.y;  // 32 x 8
#pragma unroll
  for (int i = 0; i < 32; i += 8)
    tile[ty + i][tx] = in[(size_t)(r0 + ty + i) * C + c0 + tx];
  __syncthreads();
#pragma unroll
  for (int i = 0; i < 32; i += 8)
    out[(size_t)(c0 + ty + i) * R + r0 + tx] = f2bf(tile[tx][ty + i]);
}

// ---------------- gemm_bt mainloop (128x128 tile, K=768, BK=32) ----------------

__device__ __forceinline__ void gemm_bt_mainloop(const ushort_t* __restrict__ A,
                                                 const ushort_t* __restrict__ Bt,
                                                 int m0, int n0,
                                                 ushort_t* sA, ushort_t* sB,
                                                 floatx4 acc[4][4]) {
  const int t = threadIdx.x;
  const int lane = t & 63, w = t >> 6;
  const int wr = w >> 1, wc = w & 1;
  const int lr = lane & 15, qd = lane >> 4;
  const int swz = ((t & 3) ^ ((t >> 3) & 3)) * 8;  // swizzled col chunk for staging
  const ushort_t* gA = A + (size_t)(m0 + (t >> 2)) * 768 + swz;
  const ushort_t* gB = Bt + (size_t)(n0 + (t >> 2)) * 768 + swz;
  char* lA = (char*)sA + t * 16;
  char* lB = (char*)sB + t * 16;
  const int rsz = (qd ^ ((lr >> 1) & 3)) * 16;  // swizzled chunk byte-offset for reads
  for (int k0 = 0; k0 < 768; k0 += 32) {
    __syncthreads();
    async16(gA + k0, lA);
    async16(gA + k0 + 64 * 768, lA + 4096);
    async16(gB + k0, lB);
    async16(gB + k0 + 64 * 768, lB + 4096);
    asm volatile("s_waitcnt vmcnt(0)" ::: "memory");
    __syncthreads();
    bf16x8 af[4], bfr[4];
#pragma unroll
    for (int i = 0; i < 4; ++i)
      af[i] = *(const bf16x8*)((const char*)sA + (wr * 64 + i * 16 + lr) * 64 + rsz);
#pragma unroll
    for (int j = 0; j < 4; ++j)
      bfr[j] = *(const bf16x8*)((const char*)sB + (wc * 64 + j * 16 + lr) * 64 + rsz);
#pragma unroll
    for (int i = 0; i < 4; ++i)
#pragma unroll
      for (int j = 0; j < 4; ++j)
        acc[i][j] = __builtin_amdgcn_mfma_f32_16x16x32_bf16(af[i], bfr[j], acc[i][j], 0, 0, 0);
  }
}

// ---------------- QKV GEMM + bias + zeta + scale, scatter to q/k/vt ----------------

__global__ __launch_bounds__(256) void k_qkv(const ushort_t* __restrict__ xb,
                                             const ushort_t* __restrict__ WqT,
                                             const float* __restrict__ bqkv,
                                             const float* __restrict__ zeta,
                                             ushort_t* __restrict__ qb,
                                             ushort_t* __restrict__ kb,
                                             ushort_t* __restrict__ vtb) {
  __shared__ alignas(16) ushort_t sA[128 * 32];
  __shared__ alignas(16) ushort_t sB[128 * 32];
  floatx4 acc[4][4] = {};
  const int m0 = blockIdx.y * 128, n0 = blockIdx.x * 128;
  gemm_bt_mainloop(xb, WqT, m0, n0, sA, sB, acc);
  const int t = threadIdx.x, lane = t & 63, w = t >> 6;
  const int wr = w >> 1, wc = w & 1, lr = lane & 15, qd = lane >> 4;
  const int tq = n0 / 768;  // 0=q 1=k 2=v (tile never straddles: 768 % 128 == 0)
#pragma unroll
  for (int j = 0; j < 4; ++j) {
    int n = n0 + wc * 64 + j * 16 + lr;
    int nc = n - tq * 768;
    int h = nc >> 6, dim = n & 63;
    float bias = bqkv[n];
    float zv = zeta[nc];
    // fold d^-0.5 AND log2(e) into q so attention softmax can use exp2
    float mult = (tq == 0) ? zv * 0.125f * LOG2E : zv;
    if (tq < 2) {
      ushort_t* dst = (tq == 0) ? qb : kb;
#pragma unroll
      for (int i = 0; i < 4; ++i) {
        int mbase = m0 + wr * 64 + i * 16 + qd * 4;
#pragma unroll
        for (int r = 0; r < 4; ++r) {
          int m = mbase + r;
          int b = m >> 10, seq = m & 1023;
          dst[(((size_t)b * 12 + h) * 1024 + seq) * 64 + dim] = f2bf((acc[i][j][r] + bias) * mult);
        }
      }
    } else {
#pragma unroll
      for (int i = 0; i < 4; ++i) {
        int mbase = m0 + wr * 64 + i * 16 + qd * 4;
        int b = mbase >> 10, seq = mbase & 1023;
        us4 pk;
        pk.x = f2bf((acc[i][j][0] + bias) * mult);
        pk.y = f2bf((acc[i][j][1] + bias) * mult);
        pk.z = f2bf((acc[i][j][2] + bias) * mult);
        pk.w = f2bf((acc[i][j][3] + bias) * mult);
        *(us4*)&vtb[(((size_t)b * 12 + h) * 64 + dim) * 1024 + seq] = pk;
      }
    }
  }
}

// ---------------- flash attention v3 ----------------
// S^T = K*Q^T (C-layout: col=qrow, rows=keys), O^T = Vt*P^T.
// No online max (logits bounded; softmax shift-invariant), lane-partial l,
// V frags direct global->VGPR, per-wave sP half-tiles (no barriers around P).
// LDS: sK 16 KB swizzled + per-wave sP 4x4 KB + mask 512 B = 33.3 KB -> 4 blk/CU.

__global__ __launch_bounds__(256, 4) void k_attn(const ushort_t* __restrict__ qg,
                                                 const ushort_t* __restrict__ kg,
                                                 const ushort_t* __restrict__ vg,
                                                 const unsigned char* __restrict__ mask,
                                                 ushort_t* __restrict__ ob) {
  __shared__ alignas(16) char smem[33280];
  float* maskadd = (float*)(smem + 32768);
  const int t = threadIdx.x, lane = t & 63, w = t >> 6;
  const int lr = lane & 15, qd = lane >> 4;
  // XCD swizzle: all 8 q-tiles of one bh adjacent on the same XCD (lin%8)
  const int lin = blockIdx.x;
  const int bh = (lin & 7) + 8 * (lin >> 6);
  const int qt = (lin >> 3) & 7;
  const int b = bh / 12, h = bh % 12;
  const int qrow0 = qt * 128 + w * 32;
  const ushort_t* qp = qg + (size_t)bh * 65536;
  const ushort_t* kp = kg + (size_t)bh * 65536;
  const ushort_t* vp = vg + (size_t)bh * 65536;
  const unsigned char* mp = mask + b * 1024;

  // Q fragments (B-operand of K*Q^T), kept in registers for all 8 K-tiles
  bf16x8 qf[2][2];
#pragma unroll
  for (int ns = 0; ns < 2; ++ns)
#pragma unroll
    for (int kk = 0; kk < 2; ++kk)
      qf[ns][kk] = *(const bf16x8*)(qp + (size_t)(qrow0 + ns * 16 + lr) * 64 + kk * 32 + qd * 8);

  floatx4 o[4][2] = {};
  float lst[2] = {0.f, 0.f};  // lane-partial softmax denominators
  char* sPw = smem + 16384 + w * 4096;
  const ushort_t* vrow = vp + lr * 1024 + qd * 8;  // + ds*16*1024 + key offset

  for (int kt = 0; kt < 8; ++kt) {
    __syncthreads();  // protect sK from previous iteration's readers
    const ushort_t* kpt = kp + kt * 8192;
#pragma unroll
    for (int it = 0; it < 4; ++it) {
      int p = it * 256 + t;
      int r = p >> 3, cs = (p & 7) ^ (r & 7);
      async16(kpt + r * 64 + cs * 8, smem + p * 16);
    }
    if (t < 128) maskadd[t] = mp[kt * 128 + t] ? -1e30f : 0.0f;
    asm volatile("s_waitcnt vmcnt(0)" ::: "memory");
    __syncthreads();  // sK + mask ready

#pragma unroll
    for (int hh = 0; hh < 2; ++hh) {
      // prefetch V frags for kk=0 (keys kt*128 + hh*64 + 0..31)
      bf16x8 av0[4];
#pragma unroll
      for (int ds = 0; ds < 4; ++ds)
        av0[ds] = *(const bf16x8*)(vrow + ds * 16384 + kt * 128 + hh * 64);
      // S^T quarter: 64 keys (4 msub) x 32 qrows (2 nsub)
      floatx4 s[4][2] = {};
#pragma unroll
      for (int kk = 0; kk < 2; ++kk) {
#pragma unroll
        for (int ms = 0; ms < 4; ++ms) {
          bf16x8 ak = *(const bf16x8*)(smem + ((hh * 4 + ms) * 16 + lr) * 128 +
                                       ((kk * 4 + qd) ^ (lr & 7)) * 16);
#pragma unroll
          for (int ns = 0; ns < 2; ++ns)
            s[ms][ns] = __builtin_amdgcn_mfma_f32_16x16x32_bf16(ak, qf[ns][kk], s[ms][ns], 0, 0, 0);
        }
      }
      // prefetch V frags for kk=1
      bf16x8 av1[4];
#pragma unroll
      for (int ds = 0; ds < 4; ++ds)
        av1[ds] = *(const bf16x8*)(vrow + ds * 16384 + kt * 128 + hh * 64 + 32);
      // softmax (no max subtraction): P = exp2(s + mask), lane-partial sum
#pragma unroll
      for (int ms = 0; ms < 4; ++ms) {
        float4 mk = *(const float4*)&maskadd[(hh * 4 + ms) * 16 + qd * 4];
#pragma unroll
        for (int ns = 0; ns < 2; ++ns) {
          float p0 = __builtin_amdgcn_exp2f(s[ms][ns][0] + mk.x);
          float p1 = __builtin_amdgcn_exp2f(s[ms][ns][1] + mk.y);
          float p2 = __builtin_amdgcn_exp2f(s[ms][ns][2] + mk.z);
          float p3 = __builtin_amdgcn_exp2f(s[ms][ns][3] + mk.w);
          lst[ns] += (p0 + p1) + (p2 + p3);
          uint2 pk;
          pk.x = pk_bf16(p0, p1);
          pk.y = pk_bf16(p2, p3);
          // sP half-tile: row = qrow(32) x 8 chunks of 16B (64 keys), XOR swizzle
          *(uint2*)(sPw + (ns * 16 + lr) * 128 +
                    ((ms * 2 + (qd >> 1)) ^ (lr & 7)) * 16 + (qd & 1) * 8) = pk;
        }
      }
      asm volatile("s_waitcnt lgkmcnt(0)" ::: "memory");  // wave-local P visible
      // O^T += Vt * P^T  (16 mfma per half)
#pragma unroll
      for (int kk = 0; kk < 2; ++kk) {
        bf16x8 pb[2];
#pragma unroll
        for (int ns = 0; ns < 2; ++ns)
          pb[ns] = *(const bf16x8*)(sPw + (ns * 16 + lr) * 128 +
                                    ((kk * 4 + qd) ^ (lr & 7)) * 16);
#pragma unroll
        for (int ds = 0; ds < 4; ++ds) {
          bf16x8 av = (kk == 0) ? av0[ds] : av1[ds];
#pragma unroll
          for (int ns = 0; ns < 2; ++ns)
            o[ds][ns] = __builtin_amdgcn_mfma_f32_16x16x32_bf16(av, pb[ns], o[ds][ns], 0, 0, 0);
        }
      }
    }
  }
  // epilogue: reduce l across quads, then O/l -> obuf (B,N,H*d) bf16
#pragma unroll
  for (int ns = 0; ns < 2; ++ns) {
    lst[ns] += __shfl_xor(lst[ns], 16);
    lst[ns] += __shfl_xor(lst[ns], 32);
  }
#pragma unroll
  for (int ns = 0; ns < 2; ++ns) {
    float rl = 1.0f / lst[ns];
    size_t row = (size_t)(b * 1024 + qrow0 + ns * 16 + lr) * 768 + h * 64;
#pragma unroll
    for (int ds = 0; ds < 4; ++ds) {
      uint2 ov;
      ov.x = pk_bf16(o[ds][ns][0] * rl, o[ds][ns][1] * rl);
      ov.y = pk_bf16(o[ds][ns][2] * rl, o[ds][ns][3] * rl);
      *(uint2*)&ob[row + ds * 16 + qd * 4] = ov;
    }
  }
}

// ---------------- output projection ----------------

__global__ __launch_bounds__(256) void k_proj(const ushort_t* __restrict__ ob,
                                              const ushort_t* __restrict__ WpT,
                                              const float* __restrict__ bproj,
                                              float* __restrict__ out) {
  __shared__ alignas(16) ushort_t sA[128 * 32];
  __shared__ alignas(16) ushort_t sB[128 * 32];
  floatx4 acc[4][4] = {};
  const int m0 = blockIdx.y * 128, n0 = blockIdx.x * 128;
  gemm_bt_mainloop(ob, WpT, m0, n0, sA, sB, acc);
  const int t = threadIdx.x, lane = t & 63, w = t >> 6;
  const int wr = w >> 1, wc = w & 1, lr = lane & 15, qd = lane >> 4;
#pragma unroll
  for (int j = 0; j < 4; ++j) {
    int n = n0 + wc * 64 + j * 16 + lr;
    float bias = bproj[n];
#pragma unroll
    for (int i = 0; i < 4; ++i) {
      int mbase = m0 + wr * 64 + i * 16 + qd * 4;
#pragma unroll
      for (int r = 0; r < 4; ++r)
        out[(size_t)(mbase + r) * 768 + n] = acc[i][j][r] + bias;
    }
  }
}

// ---------------- launch ----------------

extern "C" void kernel_launch(void* const* d_in, const int* in_sizes, int n_in,
                              void* d_out, int out_size, void* d_ws, size_t ws_size,
                              hipStream_t stream) {
  const float* x = (const float*)d_in[0];
  const float* bqkv = (const float*)d_in[2];
  const float* zeta = (const float*)d_in[3];
  const float* bproj = (const float*)d_in[5];
  const unsigned char* mask = (const unsigned char*)d_in[6];
  float* out = (float*)d_out;
  char* ws = (char*)d_ws;
  ushort_t* xb  = (ushort_t*)(ws);              // 16384x768 bf16
  ushort_t* WqT = (ushort_t*)(ws + 25165824);   // 2304x768 bf16
  ushort_t* WpT = (ushort_t*)(ws + 28704768);   // 768x768 bf16
  ushort_t* qb  = (ushort_t*)(ws + 29884416);   // (B,H,N,d) bf16
  ushort_t* kb  = (ushort_t*)(ws + 55050240);   // (B,H,N,d) bf16
  ushort_t* vtb = (ushort_t*)(ws + 80216064);   // (B,H,d,N) bf16
  ushort_t* ob  = xb;  // xb dead after k_qkv; reuse as attention output

  k_cvt_x<<<dim3(6144), dim3(256), 0, stream>>>(x, xb);
  k_transpose_bf16<<<dim3(72, 24), dim3(32, 8), 0, stream>>>((const float*)d_in[1], WqT, 768, 2304);
  k_transpose_bf16<<<dim3(24, 24), dim3(32, 8), 0, stream>>>((const float*)d_in[4], WpT, 768, 768);
  k_qkv<<<dim3(18, 128), dim3(256), 0, stream>>>(xb, WqT, bqkv, zeta, qb, kb, vtb);
  k_attn<<<dim3(1536), dim3(256), 0, stream>>>(qb, kb, vtb, mask, ob);
  k_proj<<<dim3(6, 128), dim3(256), 0, stream>>>(ob, WpT, bproj, out);
}

// Round 4
// 313.601 us; speedup vs baseline: 1.8034x; 1.8034x over previous
//
#include <hip/hip_runtime.h>
#include <hip/hip_bf16.h>

typedef unsigned short ushort_t;
typedef __bf16 bf16_t;
typedef bf16_t bf16x8 __attribute__((ext_vector_type(8)));
typedef float floatx4 __attribute__((ext_vector_type(4)));
typedef ushort_t ushortx8 __attribute__((ext_vector_type(8)));

struct alignas(8) us4 { ushort_t x, y, z, w; };

__device__ __forceinline__ ushort_t f2bf(float f) {
  union { float f; unsigned int u; } v; v.f = f;
  unsigned int u = v.u;
  return (ushort_t)((u + 0x7fffu + ((u >> 16) & 1u)) >> 16);
}

__device__ __forceinline__ unsigned int pk_bf16(float a, float b) {
  __hip_bfloat162 h = __float22bfloat162_rn(float2{a, b});  // .x in low half
  union { __hip_bfloat162 h; unsigned int u; } v; v.h = h;
  return v.u;
}

__device__ __forceinline__ void async16(const void* g, void* l) {
  __builtin_amdgcn_global_load_lds(
      (const __attribute__((address_space(1))) unsigned int*)g,
      (__attribute__((address_space(3))) unsigned int*)l, 16, 0, 0);
}

#define LOG2E 1.44269504088896340736f

// ---------------- convert / transpose ----------------

__global__ __launch_bounds__(256) void k_cvt_x(const float* __restrict__ in,
                                               ushort_t* __restrict__ out) {
  size_t i = ((size_t)blockIdx.x * 256 + threadIdx.x) * 8;
  float4 a = *(const float4*)(in + i);
  float4 b = *(const float4*)(in + i + 4);
  ushortx8 o;
  o[0] = f2bf(a.x); o[1] = f2bf(a.y); o[2] = f2bf(a.z); o[3] = f2bf(a.w);
  o[4] = f2bf(b.x); o[5] = f2bf(b.y); o[6] = f2bf(b.z); o[7] = f2bf(b.w);
  *(ushortx8*)(out + i) = o;
}

__global__ __launch_bounds__(256) void k_transpose_bf16(const float* __restrict__ in,
                                                        ushort_t* __restrict__ out,
                                                        int R, int C) {
  __shared__ float tile[32][33];
  int c0 = blockIdx.x * 32, r0 = blockIdx.y * 32;
  int tx = threadIdx.x, ty = threadIdx.y;  // 32 x 8
#pragma unroll
  for (int i = 0; i < 32; i += 8)
    tile[ty + i][tx] = in[(size_t)(r0 + ty + i) * C + c0 + tx];
  __syncthreads();
#pragma unroll
  for (int i = 0; i < 32; i += 8)
    out[(size_t)(c0 + ty + i) * R + r0 + tx] = f2bf(tile[tx][ty + i]);
}

// ---------------- gemm_bt mainloop (128x128 tile, K=768, BK=32) ----------------

__device__ __forceinline__ void gemm_bt_mainloop(const ushort_t* __restrict__ A,
                                                 const ushort_t* __restrict__ Bt,
                                                 int m0, int n0,
                                                 ushort_t* sA, ushort_t* sB,
                                                 floatx4 acc[4][4]) {
  const int t = threadIdx.x;
  const int lane = t & 63, w = t >> 6;
  const int wr = w >> 1, wc = w & 1;
  const int lr = lane & 15, qd = lane >> 4;
  const int swz = ((t & 3) ^ ((t >> 3) & 3)) * 8;  // swizzled col chunk for staging
  const ushort_t* gA = A + (size_t)(m0 + (t >> 2)) * 768 + swz;
  const ushort_t* gB = Bt + (size_t)(n0 + (t >> 2)) * 768 + swz;
  char* lA = (char*)sA + t * 16;
  char* lB = (char*)sB + t * 16;
  const int rsz = (qd ^ ((lr >> 1) & 3)) * 16;  // swizzled chunk byte-offset for reads
  for (int k0 = 0; k0 < 768; k0 += 32) {
    __syncthreads();
    async16(gA + k0, lA);
    async16(gA + k0 + 64 * 768, lA + 4096);
    async16(gB + k0, lB);
    async16(gB + k0 + 64 * 768, lB + 4096);
    asm volatile("s_waitcnt vmcnt(0)" ::: "memory");
    __syncthreads();
    bf16x8 af[4], bfr[4];
#pragma unroll
    for (int i = 0; i < 4; ++i)
      af[i] = *(const bf16x8*)((const char*)sA + (wr * 64 + i * 16 + lr) * 64 + rsz);
#pragma unroll
    for (int j = 0; j < 4; ++j)
      bfr[j] = *(const bf16x8*)((const char*)sB + (wc * 64 + j * 16 + lr) * 64 + rsz);
#pragma unroll
    for (int i = 0; i < 4; ++i)
#pragma unroll
      for (int j = 0; j < 4; ++j)
        acc[i][j] = __builtin_amdgcn_mfma_f32_16x16x32_bf16(af[i], bfr[j], acc[i][j], 0, 0, 0);
  }
}

// ---------------- QKV GEMM + bias + zeta + scale, scatter to q/k/vt ----------------

__global__ __launch_bounds__(256) void k_qkv(const ushort_t* __restrict__ xb,
                                             const ushort_t* __restrict__ WqT,
                                             const float* __restrict__ bqkv,
                                             const float* __restrict__ zeta,
                                             ushort_t* __restrict__ qb,
                                             ushort_t* __restrict__ kb,
                                             ushort_t* __restrict__ vtb) {
  __shared__ alignas(16) ushort_t sA[128 * 32];
  __shared__ alignas(16) ushort_t sB[128 * 32];
  floatx4 acc[4][4] = {};
  const int m0 = blockIdx.y * 128, n0 = blockIdx.x * 128;
  gemm_bt_mainloop(xb, WqT, m0, n0, sA, sB, acc);
  const int t = threadIdx.x, lane = t & 63, w = t >> 6;
  const int wr = w >> 1, wc = w & 1, lr = lane & 15, qd = lane >> 4;
  const int tq = n0 / 768;  // 0=q 1=k 2=v (tile never straddles: 768 % 128 == 0)
#pragma unroll
  for (int j = 0; j < 4; ++j) {
    int n = n0 + wc * 64 + j * 16 + lr;
    int nc = n - tq * 768;
    int h = nc >> 6, dim = n & 63;
    float bias = bqkv[n];
    float zv = zeta[nc];
    // fold d^-0.5 AND log2(e) into q so attention softmax can use exp2
    float mult = (tq == 0) ? zv * 0.125f * LOG2E : zv;
    if (tq < 2) {
      ushort_t* dst = (tq == 0) ? qb : kb;
#pragma unroll
      for (int i = 0; i < 4; ++i) {
        int mbase = m0 + wr * 64 + i * 16 + qd * 4;
#pragma unroll
        for (int r = 0; r < 4; ++r) {
          int m = mbase + r;
          int b = m >> 10, seq = m & 1023;
          dst[(((size_t)b * 12 + h) * 1024 + seq) * 64 + dim] = f2bf((acc[i][j][r] + bias) * mult);
        }
      }
    } else {
#pragma unroll
      for (int i = 0; i < 4; ++i) {
        int mbase = m0 + wr * 64 + i * 16 + qd * 4;
        int b = mbase >> 10, seq = mbase & 1023;
        us4 pk;
        pk.x = f2bf((acc[i][j][0] + bias) * mult);
        pk.y = f2bf((acc[i][j][1] + bias) * mult);
        pk.z = f2bf((acc[i][j][2] + bias) * mult);
        pk.w = f2bf((acc[i][j][3] + bias) * mult);
        *(us4*)&vtb[(((size_t)b * 12 + h) * 64 + dim) * 1024 + seq] = pk;
      }
    }
  }
}

// ---------------- flash attention v4 ----------------
// S^T = K*Q^T (C-layout: col=qrow, rows=keys), O^T = Vt*P^T.
// No online max (logits bounded; softmax shift-invariant), lane-partial l,
// per-wave sP (no barriers around P round-trip), V staged via async16 (shared,
// coalesced — round 3's direct global V loads caused 505 MB FETCH / 753 MB WRITE).
// LDS: sK 16K [0) + sP 4x4K [16384) + sV 16K [32768) + mask .5K [49152) = 48.5 KB.

__global__ __launch_bounds__(256, 3) void k_attn(const ushort_t* __restrict__ qg,
                                                 const ushort_t* __restrict__ kg,
                                                 const ushort_t* __restrict__ vg,
                                                 const unsigned char* __restrict__ mask,
                                                 ushort_t* __restrict__ ob) {
  __shared__ alignas(16) char smem[49664];
  char* sV = smem + 32768;
  float* maskadd = (float*)(smem + 49152);
  const int t = threadIdx.x, lane = t & 63, w = t >> 6;
  const int lr = lane & 15, qd = lane >> 4;
  // XCD swizzle: all 8 q-tiles of one bh adjacent on the same XCD (lin%8)
  const int lin = blockIdx.x;
  const int bh = (lin & 7) + 8 * (lin >> 6);
  const int qt = (lin >> 3) & 7;
  const int b = bh / 12, h = bh % 12;
  const int qrow0 = qt * 128 + w * 32;
  const ushort_t* qp = qg + (size_t)bh * 65536;
  const ushort_t* kp = kg + (size_t)bh * 65536;
  const ushort_t* vp = vg + (size_t)bh * 65536;
  const unsigned char* mp = mask + b * 1024;

  // Q fragments (B-operand of K*Q^T), kept in registers for all 8 K-tiles
  bf16x8 qf[2][2];
#pragma unroll
  for (int ns = 0; ns < 2; ++ns)
#pragma unroll
    for (int kk = 0; kk < 2; ++kk)
      qf[ns][kk] = *(const bf16x8*)(qp + (size_t)(qrow0 + ns * 16 + lr) * 64 + kk * 32 + qd * 8);

  floatx4 o[4][2] = {};
  float lst[2] = {0.f, 0.f};  // lane-partial softmax denominators
  char* sPw = smem + 16384 + w * 4096;

  for (int kt = 0; kt < 8; ++kt) {
    __syncthreads();  // protect sK/sV from previous iteration's readers
    // stage K: 128 rows x 8 chunks, chunk (r,c) at pos r*8 + (c ^ (r&7))
    const ushort_t* kpt = kp + kt * 8192;
#pragma unroll
    for (int it = 0; it < 4; ++it) {
      int p = it * 256 + t;
      int r = p >> 3, cs = (p & 7) ^ (r & 7);
      async16(kpt + r * 64 + cs * 8, smem + p * 16);
    }
    // stage V: 64 rows (d) x 16 chunks (keys), chunk (r,c) at pos r*16 + (c ^ (r&15))
    const ushort_t* vpt = vp + kt * 128;
#pragma unroll
    for (int it = 0; it < 4; ++it) {
      int p = it * 256 + t;
      int r = p >> 4, cs = (p & 15) ^ (r & 15);
      async16(vpt + (size_t)r * 1024 + cs * 8, sV + p * 16);
    }
    if (t < 128) maskadd[t] = mp[kt * 128 + t] ? -1e30f : 0.0f;
    asm volatile("s_waitcnt vmcnt(0)" ::: "memory");
    __syncthreads();  // sK + sV + mask ready

#pragma unroll
    for (int hh = 0; hh < 2; ++hh) {
      // S^T quarter: 64 keys (4 msub) x 32 qrows (2 nsub)
      floatx4 s[4][2] = {};
#pragma unroll
      for (int kk = 0; kk < 2; ++kk) {
#pragma unroll
        for (int ms = 0; ms < 4; ++ms) {
          bf16x8 ak = *(const bf16x8*)(smem + ((hh * 4 + ms) * 16 + lr) * 128 +
                                       ((kk * 4 + qd) ^ (lr & 7)) * 16);
#pragma unroll
          for (int ns = 0; ns < 2; ++ns)
            s[ms][ns] = __builtin_amdgcn_mfma_f32_16x16x32_bf16(ak, qf[ns][kk], s[ms][ns], 0, 0, 0);
        }
      }
      // softmax (no max subtraction): P = exp2(s + mask), lane-partial sum
#pragma unroll
      for (int ms = 0; ms < 4; ++ms) {
        float4 mk = *(const float4*)&maskadd[(hh * 4 + ms) * 16 + qd * 4];
#pragma unroll
        for (int ns = 0; ns < 2; ++ns) {
          float p0 = __builtin_amdgcn_exp2f(s[ms][ns][0] + mk.x);
          float p1 = __builtin_amdgcn_exp2f(s[ms][ns][1] + mk.y);
          float p2 = __builtin_amdgcn_exp2f(s[ms][ns][2] + mk.z);
          float p3 = __builtin_amdgcn_exp2f(s[ms][ns][3] + mk.w);
          lst[ns] += (p0 + p1) + (p2 + p3);
          uint2 pk;
          pk.x = pk_bf16(p0, p1);
          pk.y = pk_bf16(p2, p3);
          // sP half-tile: row = qrow(32) x 8 chunks of 16B (64 keys), XOR swizzle
          *(uint2*)(sPw + (ns * 16 + lr) * 128 +
                    ((ms * 2 + (qd >> 1)) ^ (lr & 7)) * 16 + (qd & 1) * 8) = pk;
        }
      }
      asm volatile("s_waitcnt lgkmcnt(0)" ::: "memory");  // wave-local P visible
      // O^T += Vt * P^T  (16 mfma per half)
#pragma unroll
      for (int kk = 0; kk < 2; ++kk) {
        bf16x8 pb[2];
#pragma unroll
        for (int ns = 0; ns < 2; ++ns)
          pb[ns] = *(const bf16x8*)(sPw + (ns * 16 + lr) * 128 +
                                    ((kk * 4 + qd) ^ (lr & 7)) * 16);
#pragma unroll
        for (int ds = 0; ds < 4; ++ds) {
          // sV row = ds*16+lr, key chunk = hh*8+kk*4+qd, swizzle ^ lr
          bf16x8 av = *(const bf16x8*)(sV + (ds * 16 + lr) * 256 +
                                       ((hh * 8 + kk * 4 + qd) ^ lr) * 16);
#pragma unroll
          for (int ns = 0; ns < 2; ++ns)
            o[ds][ns] = __builtin_amdgcn_mfma_f32_16x16x32_bf16(av, pb[ns], o[ds][ns], 0, 0, 0);
        }
      }
    }
  }
  // epilogue: reduce l across quads, then O/l -> obuf (B,N,H*d) bf16
#pragma unroll
  for (int ns = 0; ns < 2; ++ns) {
    lst[ns] += __shfl_xor(lst[ns], 16);
    lst[ns] += __shfl_xor(lst[ns], 32);
  }
#pragma unroll
  for (int ns = 0; ns < 2; ++ns) {
    float rl = 1.0f / lst[ns];
    size_t row = (size_t)(b * 1024 + qrow0 + ns * 16 + lr) * 768 + h * 64;
#pragma unroll
    for (int ds = 0; ds < 4; ++ds) {
      uint2 ov;
      ov.x = pk_bf16(o[ds][ns][0] * rl, o[ds][ns][1] * rl);
      ov.y = pk_bf16(o[ds][ns][2] * rl, o[ds][ns][3] * rl);
      *(uint2*)&ob[row + ds * 16 + qd * 4] = ov;
    }
  }
}

// ---------------- output projection ----------------

__global__ __launch_bounds__(256) void k_proj(const ushort_t* __restrict__ ob,
                                              const ushort_t* __restrict__ WpT,
                                              const float* __restrict__ bproj,
                                              float* __restrict__ out) {
  __shared__ alignas(16) ushort_t sA[128 * 32];
  __shared__ alignas(16) ushort_t sB[128 * 32];
  floatx4 acc[4][4] = {};
  const int m0 = blockIdx.y * 128, n0 = blockIdx.x * 128;
  gemm_bt_mainloop(ob, WpT, m0, n0, sA, sB, acc);
  const int t = threadIdx.x, lane = t & 63, w = t >> 6;
  const int wr = w >> 1, wc = w & 1, lr = lane & 15, qd = lane >> 4;
#pragma unroll
  for (int j = 0; j < 4; ++j) {
    int n = n0 + wc * 64 + j * 16 + lr;
    float bias = bproj[n];
#pragma unroll
    for (int i = 0; i < 4; ++i) {
      int mbase = m0 + wr * 64 + i * 16 + qd * 4;
#pragma unroll
      for (int r = 0; r < 4; ++r)
        out[(size_t)(mbase + r) * 768 + n] = acc[i][j][r] + bias;
    }
  }
}

// ---------------- launch ----------------

extern "C" void kernel_launch(void* const* d_in, const int* in_sizes, int n_in,
                              void* d_out, int out_size, void* d_ws, size_t ws_size,
                              hipStream_t stream) {
  const float* x = (const float*)d_in[0];
  const float* bqkv = (const float*)d_in[2];
  const float* zeta = (const float*)d_in[3];
  const float* bproj = (const float*)d_in[5];
  const unsigned char* mask = (const unsigned char*)d_in[6];
  float* out = (float*)d_out;
  char* ws = (char*)d_ws;
  ushort_t* xb  = (ushort_t*)(ws);              // 16384x768 bf16
  ushort_t* WqT = (ushort_t*)(ws + 25165824);   // 2304x768 bf16
  ushort_t* WpT = (ushort_t*)(ws + 28704768);   // 768x768 bf16
  ushort_t* qb  = (ushort_t*)(ws + 29884416);   // (B,H,N,d) bf16
  ushort_t* kb  = (ushort_t*)(ws + 55050240);   // (B,H,N,d) bf16
  ushort_t* vtb = (ushort_t*)(ws + 80216064);   // (B,H,d,N) bf16
  ushort_t* ob  = xb;  // xb dead after k_qkv; reuse as attention output

  k_cvt_x<<<dim3(6144), dim3(256), 0, stream>>>(x, xb);
  k_transpose_bf16<<<dim3(72, 24), dim3(32, 8), 0, stream>>>((const float*)d_in[1], WqT, 768, 2304);
  k_transpose_bf16<<<dim3(24, 24), dim3(32, 8), 0, stream>>>((const float*)d_in[4], WpT, 768, 768);
  k_qkv<<<dim3(18, 128), dim3(256), 0, stream>>>(xb, WqT, bqkv, zeta, qb, kb, vtb);
  k_attn<<<dim3(1536), dim3(256), 0, stream>>>(qb, kb, vtb, mask, ob);
  k_proj<<<dim3(6, 128), dim3(256), 0, stream>>>(ob, WpT, bproj, out);
}

// Round 5
// 307.409 us; speedup vs baseline: 1.8397x; 1.0201x over previous
//
#include <hip/hip_runtime.h>
#include <hip/hip_bf16.h>

typedef unsigned short ushort_t;
typedef __bf16 bf16_t;
typedef bf16_t bf16x8 __attribute__((ext_vector_type(8)));
typedef float floatx4 __attribute__((ext_vector_type(4)));
typedef ushort_t ushortx8 __attribute__((ext_vector_type(8)));

struct alignas(8) us4 { ushort_t x, y, z, w; };

__device__ __forceinline__ ushort_t f2bf(float f) {
  union { float f; unsigned int u; } v; v.f = f;
  unsigned int u = v.u;
  return (ushort_t)((u + 0x7fffu + ((u >> 16) & 1u)) >> 16);
}

__device__ __forceinline__ unsigned int pk_bf16(float a, float b) {
  __hip_bfloat162 h = __float22bfloat162_rn(float2{a, b});  // .x in low half
  union { __hip_bfloat162 h; unsigned int u; } v; v.h = h;
  return v.u;
}

__device__ __forceinline__ void async16(const void* g, void* l) {
  __builtin_amdgcn_global_load_lds(
      (const __attribute__((address_space(1))) unsigned int*)g,
      (__attribute__((address_space(3))) unsigned int*)l, 16, 0, 0);
}

#define LOG2E 1.44269504088896340736f

// ---------------- fused prep: cvt x -> bf16, transpose-cast W_qkv, W_proj ----
// grid: [0,6144) cvt x | [6144,7872) W_qkv 72x24 tiles | [7872,8448) W_proj 24x24

__global__ __launch_bounds__(256) void k_prep(const float* __restrict__ x,
                                              ushort_t* __restrict__ xb,
                                              const float* __restrict__ Wq,
                                              ushort_t* __restrict__ WqT,
                                              const float* __restrict__ Wp,
                                              ushort_t* __restrict__ WpT) {
  __shared__ float tile[32][33];
  const int bid = blockIdx.x, t = threadIdx.x;
  if (bid < 6144) {
    size_t i = ((size_t)bid * 256 + t) * 8;
    float4 a = *(const float4*)(x + i);
    float4 b = *(const float4*)(x + i + 4);
    ushortx8 o;
    o[0] = f2bf(a.x); o[1] = f2bf(a.y); o[2] = f2bf(a.z); o[3] = f2bf(a.w);
    o[4] = f2bf(b.x); o[5] = f2bf(b.y); o[6] = f2bf(b.z); o[7] = f2bf(b.w);
    *(ushortx8*)(xb + i) = o;
    return;
  }
  const float* in; ushort_t* out; int C, c0, r0;
  if (bid < 7872) {
    int b2 = bid - 6144;
    in = Wq; out = WqT; C = 2304;
    c0 = (b2 % 72) * 32; r0 = (b2 / 72) * 32;
  } else {
    int b3 = bid - 7872;
    in = Wp; out = WpT; C = 768;
    c0 = (b3 % 24) * 32; r0 = (b3 / 24) * 32;
  }
  const int tx = t & 31, ty = t >> 5;  // 32 x 8
#pragma unroll
  for (int i = 0; i < 32; i += 8)
    tile[ty + i][tx] = in[(size_t)(r0 + ty + i) * C + c0 + tx];
  __syncthreads();
#pragma unroll
  for (int i = 0; i < 32; i += 8)
    out[(size_t)(c0 + ty + i) * 768 + r0 + tx] = f2bf(tile[tx][ty + i]);
}

// ------ gemm_bt double-buffered mainloop (128x128 tile, K=768, BK=32) -------
// Ping-pong LDS (2 x 8 KB per matrix): prefetch DMA for iter k+1 issued at top
// of iter k, ONE vmcnt(0)+barrier per iter at the bottom. DMA latency hidden
// behind the 16-MFMA compute phase. XOR-swizzled layout (0 bank conflicts).

__device__ __forceinline__ void gemm_bt_dbuf(const ushort_t* __restrict__ A,
                                             const ushort_t* __restrict__ Bt,
                                             int m0, int n0,
                                             ushort_t* sA, ushort_t* sB,
                                             floatx4 acc[4][4]) {
  const int t = threadIdx.x;
  const int lane = t & 63, w = t >> 6;
  const int wr = w >> 1, wc = w & 1;
  const int lr = lane & 15, qd = lane >> 4;
  const int swz = ((t & 3) ^ ((t >> 3) & 3)) * 8;  // swizzled col chunk for staging
  const ushort_t* gA = A + (size_t)(m0 + (t >> 2)) * 768 + swz;
  const ushort_t* gB = Bt + (size_t)(n0 + (t >> 2)) * 768 + swz;
  char* lA = (char*)sA + t * 16;
  char* lB = (char*)sB + t * 16;
  const int rsz = (qd ^ ((lr >> 1) & 3)) * 16;  // swizzled chunk byte-offset for reads
  // prologue: stage k=0 into buffer 0
  async16(gA, lA);
  async16(gA + 64 * 768, lA + 4096);
  async16(gB, lB);
  async16(gB + 64 * 768, lB + 4096);
  asm volatile("s_waitcnt vmcnt(0)" ::: "memory");
  __syncthreads();
#pragma unroll 2
  for (int k = 0; k < 24; ++k) {
    const int p = k & 1, pn = p ^ 1;
    if (k < 23) {  // prefetch k+1 into the other buffer (overlaps MFMA below)
      const int k0 = (k + 1) * 32;
      async16(gA + k0, lA + pn * 8192);
      async16(gA + k0 + 64 * 768, lA + pn * 8192 + 4096);
      async16(gB + k0, lB + pn * 8192);
      async16(gB + k0 + 64 * 768, lB + pn * 8192 + 4096);
    }
    const char* cA = (const char*)sA + p * 8192;
    const char* cB = (const char*)sB + p * 8192;
    bf16x8 af[4], bfr[4];
#pragma unroll
    for (int i = 0; i < 4; ++i)
      af[i] = *(const bf16x8*)(cA + (wr * 64 + i * 16 + lr) * 64 + rsz);
#pragma unroll
    for (int j = 0; j < 4; ++j)
      bfr[j] = *(const bf16x8*)(cB + (wc * 64 + j * 16 + lr) * 64 + rsz);
#pragma unroll
    for (int i = 0; i < 4; ++i)
#pragma unroll
      for (int j = 0; j < 4; ++j)
        acc[i][j] = __builtin_amdgcn_mfma_f32_16x16x32_bf16(af[i], bfr[j], acc[i][j], 0, 0, 0);
    asm volatile("s_waitcnt vmcnt(0)" ::: "memory");  // prefetch landed
    __syncthreads();
  }
}

// ---------------- QKV GEMM + bias + zeta + scale, scatter to q/k/vt ----------------

__global__ __launch_bounds__(256, 4) void k_qkv(const ushort_t* __restrict__ xb,
                                                const ushort_t* __restrict__ WqT,
                                                const float* __restrict__ bqkv,
                                                const float* __restrict__ zeta,
                                                ushort_t* __restrict__ qb,
                                                ushort_t* __restrict__ kb,
                                                ushort_t* __restrict__ vtb) {
  __shared__ alignas(16) ushort_t sA[2 * 128 * 32];
  __shared__ alignas(16) ushort_t sB[2 * 128 * 32];
  floatx4 acc[4][4] = {};
  const int m0 = blockIdx.y * 128, n0 = blockIdx.x * 128;
  gemm_bt_dbuf(xb, WqT, m0, n0, sA, sB, acc);
  const int t = threadIdx.x, lane = t & 63, w = t >> 6;
  const int wr = w >> 1, wc = w & 1, lr = lane & 15, qd = lane >> 4;
  const int tq = n0 / 768;  // 0=q 1=k 2=v (tile never straddles: 768 % 128 == 0)
#pragma unroll
  for (int j = 0; j < 4; ++j) {
    int n = n0 + wc * 64 + j * 16 + lr;
    int nc = n - tq * 768;
    int h = nc >> 6, dim = n & 63;
    float bias = bqkv[n];
    float zv = zeta[nc];
    // fold d^-0.5 AND log2(e) into q so attention softmax can use exp2
    float mult = (tq == 0) ? zv * 0.125f * LOG2E : zv;
    if (tq < 2) {
      ushort_t* dst = (tq == 0) ? qb : kb;
#pragma unroll
      for (int i = 0; i < 4; ++i) {
        int mbase = m0 + wr * 64 + i * 16 + qd * 4;
#pragma unroll
        for (int r = 0; r < 4; ++r) {
          int m = mbase + r;
          int b = m >> 10, seq = m & 1023;
          dst[(((size_t)b * 12 + h) * 1024 + seq) * 64 + dim] = f2bf((acc[i][j][r] + bias) * mult);
        }
      }
    } else {
#pragma unroll
      for (int i = 0; i < 4; ++i) {
        int mbase = m0 + wr * 64 + i * 16 + qd * 4;
        int b = mbase >> 10, seq = mbase & 1023;
        us4 pk;
        pk.x = f2bf((acc[i][j][0] + bias) * mult);
        pk.y = f2bf((acc[i][j][1] + bias) * mult);
        pk.z = f2bf((acc[i][j][2] + bias) * mult);
        pk.w = f2bf((acc[i][j][3] + bias) * mult);
        *(us4*)&vtb[(((size_t)b * 12 + h) * 64 + dim) * 1024 + seq] = pk;
      }
    }
  }
}

// ---------------- flash attention v4 (unchanged from round 4) ----------------
// LDS: sK 16K [0) + sP 4x4K [16384) + sV 16K [32768) + mask .5K [49152) = 48.5 KB.

__global__ __launch_bounds__(256, 3) void k_attn(const ushort_t* __restrict__ qg,
                                                 const ushort_t* __restrict__ kg,
                                                 const ushort_t* __restrict__ vg,
                                                 const unsigned char* __restrict__ mask,
                                                 ushort_t* __restrict__ ob) {
  __shared__ alignas(16) char smem[49664];
  char* sV = smem + 32768;
  float* maskadd = (float*)(smem + 49152);
  const int t = threadIdx.x, lane = t & 63, w = t >> 6;
  const int lr = lane & 15, qd = lane >> 4;
  const int lin = blockIdx.x;
  const int bh = (lin & 7) + 8 * (lin >> 6);
  const int qt = (lin >> 3) & 7;
  const int b = bh / 12, h = bh % 12;
  const int qrow0 = qt * 128 + w * 32;
  const ushort_t* qp = qg + (size_t)bh * 65536;
  const ushort_t* kp = kg + (size_t)bh * 65536;
  const ushort_t* vp = vg + (size_t)bh * 65536;
  const unsigned char* mp = mask + b * 1024;

  bf16x8 qf[2][2];
#pragma unroll
  for (int ns = 0; ns < 2; ++ns)
#pragma unroll
    for (int kk = 0; kk < 2; ++kk)
      qf[ns][kk] = *(const bf16x8*)(qp + (size_t)(qrow0 + ns * 16 + lr) * 64 + kk * 32 + qd * 8);

  floatx4 o[4][2] = {};
  float lst[2] = {0.f, 0.f};
  char* sPw = smem + 16384 + w * 4096;

  for (int kt = 0; kt < 8; ++kt) {
    __syncthreads();
    const ushort_t* kpt = kp + kt * 8192;
#pragma unroll
    for (int it = 0; it < 4; ++it) {
      int p = it * 256 + t;
      int r = p >> 3, cs = (p & 7) ^ (r & 7);
      async16(kpt + r * 64 + cs * 8, smem + p * 16);
    }
    const ushort_t* vpt = vp + kt * 128;
#pragma unroll
    for (int it = 0; it < 4; ++it) {
      int p = it * 256 + t;
      int r = p >> 4, cs = (p & 15) ^ (r & 15);
      async16(vpt + (size_t)r * 1024 + cs * 8, sV + p * 16);
    }
    if (t < 128) maskadd[t] = mp[kt * 128 + t] ? -1e30f : 0.0f;
    asm volatile("s_waitcnt vmcnt(0)" ::: "memory");
    __syncthreads();

#pragma unroll
    for (int hh = 0; hh < 2; ++hh) {
      floatx4 s[4][2] = {};
#pragma unroll
      for (int kk = 0; kk < 2; ++kk) {
#pragma unroll
        for (int ms = 0; ms < 4; ++ms) {
          bf16x8 ak = *(const bf16x8*)(smem + ((hh * 4 + ms) * 16 + lr) * 128 +
                                       ((kk * 4 + qd) ^ (lr & 7)) * 16);
#pragma unroll
          for (int ns = 0; ns < 2; ++ns)
            s[ms][ns] = __builtin_amdgcn_mfma_f32_16x16x32_bf16(ak, qf[ns][kk], s[ms][ns], 0, 0, 0);
        }
      }
#pragma unroll
      for (int ms = 0; ms < 4; ++ms) {
        float4 mk = *(const float4*)&maskadd[(hh * 4 + ms) * 16 + qd * 4];
#pragma unroll
        for (int ns = 0; ns < 2; ++ns) {
          float p0 = __builtin_amdgcn_exp2f(s[ms][ns][0] + mk.x);
          float p1 = __builtin_amdgcn_exp2f(s[ms][ns][1] + mk.y);
          float p2 = __builtin_amdgcn_exp2f(s[ms][ns][2] + mk.z);
          float p3 = __builtin_amdgcn_exp2f(s[ms][ns][3] + mk.w);
          lst[ns] += (p0 + p1) + (p2 + p3);
          uint2 pk;
          pk.x = pk_bf16(p0, p1);
          pk.y = pk_bf16(p2, p3);
          *(uint2*)(sPw + (ns * 16 + lr) * 128 +
                    ((ms * 2 + (qd >> 1)) ^ (lr & 7)) * 16 + (qd & 1) * 8) = pk;
        }
      }
      asm volatile("s_waitcnt lgkmcnt(0)" ::: "memory");
#pragma unroll
      for (int kk = 0; kk < 2; ++kk) {
        bf16x8 pb[2];
#pragma unroll
        for (int ns = 0; ns < 2; ++ns)
          pb[ns] = *(const bf16x8*)(sPw + (ns * 16 + lr) * 128 +
                                    ((kk * 4 + qd) ^ (lr & 7)) * 16);
#pragma unroll
        for (int ds = 0; ds < 4; ++ds) {
          bf16x8 av = *(const bf16x8*)(sV + (ds * 16 + lr) * 256 +
                                       ((hh * 8 + kk * 4 + qd) ^ lr) * 16);
#pragma unroll
          for (int ns = 0; ns < 2; ++ns)
            o[ds][ns] = __builtin_amdgcn_mfma_f32_16x16x32_bf16(av, pb[ns], o[ds][ns], 0, 0, 0);
        }
      }
    }
  }
#pragma unroll
  for (int ns = 0; ns < 2; ++ns) {
    lst[ns] += __shfl_xor(lst[ns], 16);
    lst[ns] += __shfl_xor(lst[ns], 32);
  }
#pragma unroll
  for (int ns = 0; ns < 2; ++ns) {
    float rl = 1.0f / lst[ns];
    size_t row = (size_t)(b * 1024 + qrow0 + ns * 16 + lr) * 768 + h * 64;
#pragma unroll
    for (int ds = 0; ds < 4; ++ds) {
      uint2 ov;
      ov.x = pk_bf16(o[ds][ns][0] * rl, o[ds][ns][1] * rl);
      ov.y = pk_bf16(o[ds][ns][2] * rl, o[ds][ns][3] * rl);
      *(uint2*)&ob[row + ds * 16 + qd * 4] = ov;
    }
  }
}

// ---------------- output projection ----------------

__global__ __launch_bounds__(256, 4) void k_proj(const ushort_t* __restrict__ ob,
                                                 const ushort_t* __restrict__ WpT,
                                                 const float* __restrict__ bproj,
                                                 float* __restrict__ out) {
  __shared__ alignas(16) ushort_t sA[2 * 128 * 32];
  __shared__ alignas(16) ushort_t sB[2 * 128 * 32];
  floatx4 acc[4][4] = {};
  const int m0 = blockIdx.y * 128, n0 = blockIdx.x * 128;
  gemm_bt_dbuf(ob, WpT, m0, n0, sA, sB, acc);
  const int t = threadIdx.x, lane = t & 63, w = t >> 6;
  const int wr = w >> 1, wc = w & 1, lr = lane & 15, qd = lane >> 4;
#pragma unroll
  for (int j = 0; j < 4; ++j) {
    int n = n0 + wc * 64 + j * 16 + lr;
    float bias = bproj[n];
#pragma unroll
    for (int i = 0; i < 4; ++i) {
      int mbase = m0 + wr * 64 + i * 16 + qd * 4;
#pragma unroll
      for (int r = 0; r < 4; ++r)
        out[(size_t)(mbase + r) * 768 + n] = acc[i][j][r] + bias;
    }
  }
}

// ---------------- launch ----------------

extern "C" void kernel_launch(void* const* d_in, const int* in_sizes, int n_in,
                              void* d_out, int out_size, void* d_ws, size_t ws_size,
                              hipStream_t stream) {
  const float* x = (const float*)d_in[0];
  const float* bqkv = (const float*)d_in[2];
  const float* zeta = (const float*)d_in[3];
  const float* bproj = (const float*)d_in[5];
  const unsigned char* mask = (const unsigned char*)d_in[6];
  float* out = (float*)d_out;
  char* ws = (char*)d_ws;
  ushort_t* xb  = (ushort_t*)(ws);              // 16384x768 bf16
  ushort_t* WqT = (ushort_t*)(ws + 25165824);   // 2304x768 bf16
  ushort_t* WpT = (ushort_t*)(ws + 28704768);   // 768x768 bf16
  ushort_t* qb  = (ushort_t*)(ws + 29884416);   // (B,H,N,d) bf16
  ushort_t* kb  = (ushort_t*)(ws + 55050240);   // (B,H,N,d) bf16
  ushort_t* vtb = (ushort_t*)(ws + 80216064);   // (B,H,d,N) bf16
  ushort_t* ob  = xb;  // xb dead after k_qkv; reuse as attention output

  k_prep<<<dim3(8448), dim3(256), 0, stream>>>(x, xb, (const float*)d_in[1], WqT,
                                               (const float*)d_in[4], WpT);
  k_qkv<<<dim3(18, 128), dim3(256), 0, stream>>>(xb, WqT, bqkv, zeta, qb, kb, vtb);
  k_attn<<<dim3(1536), dim3(256), 0, stream>>>(qb, kb, vtb, mask, ob);
  k_proj<<<dim3(6, 128), dim3(256), 0, stream>>>(ob, WpT, bproj, out);
}

// Round 6
// 290.507 us; speedup vs baseline: 1.9467x; 1.0582x over previous
//
#include <hip/hip_runtime.h>
#include <hip/hip_bf16.h>

typedef unsigned short ushort_t;
typedef __bf16 bf16_t;
typedef bf16_t bf16x8 __attribute__((ext_vector_type(8)));
typedef float floatx4 __attribute__((ext_vector_type(4)));
typedef ushort_t ushortx8 __attribute__((ext_vector_type(8)));

struct alignas(8) us4 { ushort_t x, y, z, w; };

__device__ __forceinline__ ushort_t f2bf(float f) {
  union { float f; unsigned int u; } v; v.f = f;
  unsigned int u = v.u;
  return (ushort_t)((u + 0x7fffu + ((u >> 16) & 1u)) >> 16);
}

__device__ __forceinline__ unsigned int pk_bf16(float a, float b) {
  __hip_bfloat162 h = __float22bfloat162_rn(float2{a, b});  // .x in low half
  union { __hip_bfloat162 h; unsigned int u; } v; v.h = h;
  return v.u;
}

__device__ __forceinline__ void async16(const void* g, void* l) {
  __builtin_amdgcn_global_load_lds(
      (const __attribute__((address_space(1))) unsigned int*)g,
      (__attribute__((address_space(3))) unsigned int*)l, 16, 0, 0);
}

#define LOG2E 1.44269504088896340736f

// ---------------- fused prep: cvt x -> bf16, transpose-cast W_qkv, W_proj ----

__global__ __launch_bounds__(256) void k_prep(const float* __restrict__ x,
                                              ushort_t* __restrict__ xb,
                                              const float* __restrict__ Wq,
                                              ushort_t* __restrict__ WqT,
                                              const float* __restrict__ Wp,
                                              ushort_t* __restrict__ WpT) {
  __shared__ float tile[32][33];
  const int bid = blockIdx.x, t = threadIdx.x;
  if (bid < 6144) {
    size_t i = ((size_t)bid * 256 + t) * 8;
    float4 a = *(const float4*)(x + i);
    float4 b = *(const float4*)(x + i + 4);
    ushortx8 o;
    o[0] = f2bf(a.x); o[1] = f2bf(a.y); o[2] = f2bf(a.z); o[3] = f2bf(a.w);
    o[4] = f2bf(b.x); o[5] = f2bf(b.y); o[6] = f2bf(b.z); o[7] = f2bf(b.w);
    *(ushortx8*)(xb + i) = o;
    return;
  }
  const float* in; ushort_t* out; int C, c0, r0;
  if (bid < 7872) {
    int b2 = bid - 6144;
    in = Wq; out = WqT; C = 2304;
    c0 = (b2 % 72) * 32; r0 = (b2 / 72) * 32;
  } else {
    int b3 = bid - 7872;
    in = Wp; out = WpT; C = 768;
    c0 = (b3 % 24) * 32; r0 = (b3 / 24) * 32;
  }
  const int tx = t & 31, ty = t >> 5;  // 32 x 8
#pragma unroll
  for (int i = 0; i < 32; i += 8)
    tile[ty + i][tx] = in[(size_t)(r0 + ty + i) * C + c0 + tx];
  __syncthreads();
#pragma unroll
  for (int i = 0; i < 32; i += 8)
    out[(size_t)(c0 + ty + i) * 768 + r0 + tx] = f2bf(tile[tx][ty + i]);
}

// ------ gemm_bt 3-stage pipelined mainloop (128x128 tile, K=768, BK=32) -----
// 3 LDS buffers, prefetch 2 iterations ahead, end-of-iter s_waitcnt vmcnt(4)
// (waits ONLY the k+1 loads; k+2's stay in flight) + raw s_barrier — avoids
// __syncthreads' forced vmcnt(0) drain. Fully unrolled so waitcnt is static.
// Buffer p=k%3 read at iter k is next DMA-written by the prefetch issued at
// iter k+1 (after the iter-k barrier) — safe. XOR-swizzle: 0 bank conflicts.

__device__ __forceinline__ void gemm_pipe3(const ushort_t* __restrict__ A,
                                           const ushort_t* __restrict__ Bt,
                                           int m0, int n0,
                                           ushort_t* sA, ushort_t* sB,
                                           floatx4 acc[4][4]) {
  const int t = threadIdx.x;
  const int lane = t & 63, w = t >> 6;
  const int wr = w >> 1, wc = w & 1;
  const int lr = lane & 15, qd = lane >> 4;
  const int swz = ((t & 3) ^ ((t >> 3) & 3)) * 8;
  const ushort_t* gA = A + (size_t)(m0 + (t >> 2)) * 768 + swz;
  const ushort_t* gB = Bt + (size_t)(n0 + (t >> 2)) * 768 + swz;
  char* lA = (char*)sA + t * 16;
  char* lB = (char*)sB + t * 16;
  const int rsz = (qd ^ ((lr >> 1) & 3)) * 16;
#define ISSUE(kk, buf)                                    \
  do {                                                    \
    const int k0_ = (kk) * 32, b_ = (buf) * 8192;         \
    async16(gA + k0_, lA + b_);                           \
    async16(gA + k0_ + 64 * 768, lA + b_ + 4096);         \
    async16(gB + k0_, lB + b_);                           \
    async16(gB + k0_ + 64 * 768, lB + b_ + 4096);         \
  } while (0)
  ISSUE(0, 0);
  ISSUE(1, 1);
  asm volatile("s_waitcnt vmcnt(4)" ::: "memory");  // k=0 landed
  asm volatile("s_barrier" ::: "memory");
#pragma unroll
  for (int k = 0; k < 24; ++k) {
    if (k + 2 < 24) ISSUE(k + 2, (k + 2) % 3);
    const char* cA = (const char*)sA + (k % 3) * 8192;
    const char* cB = (const char*)sB + (k % 3) * 8192;
    bf16x8 af[4], bfr[4];
#pragma unroll
    for (int i = 0; i < 4; ++i)
      af[i] = *(const bf16x8*)(cA + (wr * 64 + i * 16 + lr) * 64 + rsz);
#pragma unroll
    for (int j = 0; j < 4; ++j)
      bfr[j] = *(const bf16x8*)(cB + (wc * 64 + j * 16 + lr) * 64 + rsz);
#pragma unroll
    for (int i = 0; i < 4; ++i)
#pragma unroll
      for (int j = 0; j < 4; ++j)
        acc[i][j] = __builtin_amdgcn_mfma_f32_16x16x32_bf16(af[i], bfr[j], acc[i][j], 0, 0, 0);
    if (k < 22)
      asm volatile("s_waitcnt vmcnt(4)" ::: "memory");  // k+1 landed, k+2 in flight
    else if (k == 22)
      asm volatile("s_waitcnt vmcnt(0)" ::: "memory");  // only k=23's remain
    if (k < 23) asm volatile("s_barrier" ::: "memory");
  }
#undef ISSUE
}

// ---------------- QKV GEMM + bias + zeta + scale, scatter to q/k/vt ----------------
// XCD swizzle: per XCD, 16 consecutive blocks share an n-tile and cycle 16
// m-panels -> L2 working set ~3.3 MB (16 panels + 1 weight tile) < 4 MB.

__global__ __launch_bounds__(256, 3) void k_qkv(const ushort_t* __restrict__ xb,
                                                const ushort_t* __restrict__ WqT,
                                                const float* __restrict__ bqkv,
                                                const float* __restrict__ zeta,
                                                ushort_t* __restrict__ qb,
                                                ushort_t* __restrict__ kb,
                                                ushort_t* __restrict__ vtb) {
  __shared__ alignas(16) ushort_t sA[3 * 4096];
  __shared__ alignas(16) ushort_t sB[3 * 4096];
  floatx4 acc[4][4] = {};
  const int lin = blockIdx.x;
  const int xcd = lin & 7, idx = lin >> 3;           // idx in 0..287
  const int m0 = (xcd * 16 + (idx & 15)) * 128;      // 128 m-panels
  const int n0 = (idx >> 4) * 128;                   // 18 n-tiles
  gemm_pipe3(xb, WqT, m0, n0, sA, sB, acc);
  const int t = threadIdx.x, lane = t & 63, w = t >> 6;
  const int wr = w >> 1, wc = w & 1, lr = lane & 15, qd = lane >> 4;
  const int tq = n0 / 768;  // 0=q 1=k 2=v (tile never straddles: 768 % 128 == 0)
#pragma unroll
  for (int j = 0; j < 4; ++j) {
    int n = n0 + wc * 64 + j * 16 + lr;
    int nc = n - tq * 768;
    int h = nc >> 6, dim = n & 63;
    float bias = bqkv[n];
    float zv = zeta[nc];
    float mult = (tq == 0) ? zv * 0.125f * LOG2E : zv;
    if (tq < 2) {
      ushort_t* dst = (tq == 0) ? qb : kb;
#pragma unroll
      for (int i = 0; i < 4; ++i) {
        int mbase = m0 + wr * 64 + i * 16 + qd * 4;
#pragma unroll
        for (int r = 0; r < 4; ++r) {
          int m = mbase + r;
          int b = m >> 10, seq = m & 1023;
          dst[(((size_t)b * 12 + h) * 1024 + seq) * 64 + dim] = f2bf((acc[i][j][r] + bias) * mult);
        }
      }
    } else {
#pragma unroll
      for (int i = 0; i < 4; ++i) {
        int mbase = m0 + wr * 64 + i * 16 + qd * 4;
        int b = mbase >> 10, seq = mbase & 1023;
        us4 pk;
        pk.x = f2bf((acc[i][j][0] + bias) * mult);
        pk.y = f2bf((acc[i][j][1] + bias) * mult);
        pk.z = f2bf((acc[i][j][2] + bias) * mult);
        pk.w = f2bf((acc[i][j][3] + bias) * mult);
        *(us4*)&vtb[(((size_t)b * 12 + h) * 64 + dim) * 1024 + seq] = pk;
      }
    }
  }
}

// ---------------- flash attention v4 (unchanged from round 4/5) --------------

__global__ __launch_bounds__(256, 3) void k_attn(const ushort_t* __restrict__ qg,
                                                 const ushort_t* __restrict__ kg,
                                                 const ushort_t* __restrict__ vg,
                                                 const unsigned char* __restrict__ mask,
                                                 ushort_t* __restrict__ ob) {
  __shared__ alignas(16) char smem[49664];
  char* sV = smem + 32768;
  float* maskadd = (float*)(smem + 49152);
  const int t = threadIdx.x, lane = t & 63, w = t >> 6;
  const int lr = lane & 15, qd = lane >> 4;
  const int lin = blockIdx.x;
  const int bh = (lin & 7) + 8 * (lin >> 6);
  const int qt = (lin >> 3) & 7;
  const int b = bh / 12, h = bh % 12;
  const int qrow0 = qt * 128 + w * 32;
  const ushort_t* qp = qg + (size_t)bh * 65536;
  const ushort_t* kp = kg + (size_t)bh * 65536;
  const ushort_t* vp = vg + (size_t)bh * 65536;
  const unsigned char* mp = mask + b * 1024;

  bf16x8 qf[2][2];
#pragma unroll
  for (int ns = 0; ns < 2; ++ns)
#pragma unroll
    for (int kk = 0; kk < 2; ++kk)
      qf[ns][kk] = *(const bf16x8*)(qp + (size_t)(qrow0 + ns * 16 + lr) * 64 + kk * 32 + qd * 8);

  floatx4 o[4][2] = {};
  float lst[2] = {0.f, 0.f};
  char* sPw = smem + 16384 + w * 4096;

  for (int kt = 0; kt < 8; ++kt) {
    __syncthreads();
    const ushort_t* kpt = kp + kt * 8192;
#pragma unroll
    for (int it = 0; it < 4; ++it) {
      int p = it * 256 + t;
      int r = p >> 3, cs = (p & 7) ^ (r & 7);
      async16(kpt + r * 64 + cs * 8, smem + p * 16);
    }
    const ushort_t* vpt = vp + kt * 128;
#pragma unroll
    for (int it = 0; it < 4; ++it) {
      int p = it * 256 + t;
      int r = p >> 4, cs = (p & 15) ^ (r & 15);
      async16(vpt + (size_t)r * 1024 + cs * 8, sV + p * 16);
    }
    if (t < 128) maskadd[t] = mp[kt * 128 + t] ? -1e30f : 0.0f;
    asm volatile("s_waitcnt vmcnt(0)" ::: "memory");
    __syncthreads();

#pragma unroll
    for (int hh = 0; hh < 2; ++hh) {
      floatx4 s[4][2] = {};
#pragma unroll
      for (int kk = 0; kk < 2; ++kk) {
#pragma unroll
        for (int ms = 0; ms < 4; ++ms) {
          bf16x8 ak = *(const bf16x8*)(smem + ((hh * 4 + ms) * 16 + lr) * 128 +
                                       ((kk * 4 + qd) ^ (lr & 7)) * 16);
#pragma unroll
          for (int ns = 0; ns < 2; ++ns)
            s[ms][ns] = __builtin_amdgcn_mfma_f32_16x16x32_bf16(ak, qf[ns][kk], s[ms][ns], 0, 0, 0);
        }
      }
#pragma unroll
      for (int ms = 0; ms < 4; ++ms) {
        float4 mk = *(const float4*)&maskadd[(hh * 4 + ms) * 16 + qd * 4];
#pragma unroll
        for (int ns = 0; ns < 2; ++ns) {
          float p0 = __builtin_amdgcn_exp2f(s[ms][ns][0] + mk.x);
          float p1 = __builtin_amdgcn_exp2f(s[ms][ns][1] + mk.y);
          float p2 = __builtin_amdgcn_exp2f(s[ms][ns][2] + mk.z);
          float p3 = __builtin_amdgcn_exp2f(s[ms][ns][3] + mk.w);
          lst[ns] += (p0 + p1) + (p2 + p3);
          uint2 pk;
          pk.x = pk_bf16(p0, p1);
          pk.y = pk_bf16(p2, p3);
          *(uint2*)(sPw + (ns * 16 + lr) * 128 +
                    ((ms * 2 + (qd >> 1)) ^ (lr & 7)) * 16 + (qd & 1) * 8) = pk;
        }
      }
      asm volatile("s_waitcnt lgkmcnt(0)" ::: "memory");
#pragma unroll
      for (int kk = 0; kk < 2; ++kk) {
        bf16x8 pb[2];
#pragma unroll
        for (int ns = 0; ns < 2; ++ns)
          pb[ns] = *(const bf16x8*)(sPw + (ns * 16 + lr) * 128 +
                                    ((kk * 4 + qd) ^ (lr & 7)) * 16);
#pragma unroll
        for (int ds = 0; ds < 4; ++ds) {
          bf16x8 av = *(const bf16x8*)(sV + (ds * 16 + lr) * 256 +
                                       ((hh * 8 + kk * 4 + qd) ^ lr) * 16);
#pragma unroll
          for (int ns = 0; ns < 2; ++ns)
            o[ds][ns] = __builtin_amdgcn_mfma_f32_16x16x32_bf16(av, pb[ns], o[ds][ns], 0, 0, 0);
        }
      }
    }
  }
#pragma unroll
  for (int ns = 0; ns < 2; ++ns) {
    lst[ns] += __shfl_xor(lst[ns], 16);
    lst[ns] += __shfl_xor(lst[ns], 32);
  }
#pragma unroll
  for (int ns = 0; ns < 2; ++ns) {
    float rl = 1.0f / lst[ns];
    size_t row = (size_t)(b * 1024 + qrow0 + ns * 16 + lr) * 768 + h * 64;
#pragma unroll
    for (int ds = 0; ds < 4; ++ds) {
      uint2 ov;
      ov.x = pk_bf16(o[ds][ns][0] * rl, o[ds][ns][1] * rl);
      ov.y = pk_bf16(o[ds][ns][2] * rl, o[ds][ns][3] * rl);
      *(uint2*)&ob[row + ds * 16 + qd * 4] = ov;
    }
  }
}

// ---------------- output projection ----------------

__global__ __launch_bounds__(256, 3) void k_proj(const ushort_t* __restrict__ ob,
                                                 const ushort_t* __restrict__ WpT,
                                                 const float* __restrict__ bproj,
                                                 float* __restrict__ out) {
  __shared__ alignas(16) ushort_t sA[3 * 4096];
  __shared__ alignas(16) ushort_t sB[3 * 4096];
  floatx4 acc[4][4] = {};
  const int lin = blockIdx.x;
  const int xcd = lin & 7, idx = lin >> 3;           // idx in 0..95
  const int m0 = (xcd * 16 + (idx & 15)) * 128;
  const int n0 = (idx >> 4) * 128;                   // 6 n-tiles
  gemm_pipe3(ob, WpT, m0, n0, sA, sB, acc);
  const int t = threadIdx.x, lane = t & 63, w = t >> 6;
  const int wr = w >> 1, wc = w & 1, lr = lane & 15, qd = lane >> 4;
#pragma unroll
  for (int j = 0; j < 4; ++j) {
    int n = n0 + wc * 64 + j * 16 + lr;
    float bias = bproj[n];
#pragma unroll
    for (int i = 0; i < 4; ++i) {
      int mbase = m0 + wr * 64 + i * 16 + qd * 4;
#pragma unroll
      for (int r = 0; r < 4; ++r)
        out[(size_t)(mbase + r) * 768 + n] = acc[i][j][r] + bias;
    }
  }
}

// ---------------- launch ----------------

extern "C" void kernel_launch(void* const* d_in, const int* in_sizes, int n_in,
                              void* d_out, int out_size, void* d_ws, size_t ws_size,
                              hipStream_t stream) {
  const float* x = (const float*)d_in[0];
  const float* bqkv = (const float*)d_in[2];
  const float* zeta = (const float*)d_in[3];
  const float* bproj = (const float*)d_in[5];
  const unsigned char* mask = (const unsigned char*)d_in[6];
  float* out = (float*)d_out;
  char* ws = (char*)d_ws;
  ushort_t* xb  = (ushort_t*)(ws);              // 16384x768 bf16
  ushort_t* WqT = (ushort_t*)(ws + 25165824);   // 2304x768 bf16
  ushort_t* WpT = (ushort_t*)(ws + 28704768);   // 768x768 bf16
  ushort_t* qb  = (ushort_t*)(ws + 29884416);   // (B,H,N,d) bf16
  ushort_t* kb  = (ushort_t*)(ws + 55050240);   // (B,H,N,d) bf16
  ushort_t* vtb = (ushort_t*)(ws + 80216064);   // (B,H,d,N) bf16
  ushort_t* ob  = xb;  // xb dead after k_qkv; reuse as attention output

  k_prep<<<dim3(8448), dim3(256), 0, stream>>>(x, xb, (const float*)d_in[1], WqT,
                                               (const float*)d_in[4], WpT);
  k_qkv<<<dim3(2304), dim3(256), 0, stream>>>(xb, WqT, bqkv, zeta, qb, kb, vtb);
  k_attn<<<dim3(1536), dim3(256), 0, stream>>>(qb, kb, vtb, mask, ob);
  k_proj<<<dim3(768), dim3(256), 0, stream>>>(ob, WpT, bproj, out);
}